// Round 1
// baseline (150.131 us; speedup 1.0000x reference)
//
#include <hip/hip_runtime.h>

typedef __attribute__((ext_vector_type(8))) short short8;
typedef __attribute__((ext_vector_type(4))) float f32x4;

#define B_DIM 2048
#define P_DIM 2048
#define R_DIM 4096
#define H_DIM 6
#define M_DIM 256
#define A_DIM 256
#define OUT_STRIDE 2560   // P + M + A

static __device__ __forceinline__ unsigned short f2bf(float f) {
    unsigned u = __builtin_bit_cast(unsigned, f);
    u += 0x7fffu + ((u >> 16) & 1u);          // round-to-nearest-even
    return (unsigned short)(u >> 16);
}

// ---------------------------------------------------------------------------
// Prep 1: GAT[n][k] = bf16(is_toM[k] * Gamma_AtoM[k][n]) (and GBT from is_toA,
// Gamma_MtoA). 32x32 LDS tile transpose. grid (K/32, N/32, 2), block 256.
// ---------------------------------------------------------------------------
__global__ __launch_bounds__(256) void prep_transpose(
    const float* __restrict__ GA, const float* __restrict__ GB,
    const float* __restrict__ isM, const float* __restrict__ isA,
    unsigned short* __restrict__ GAT, unsigned short* __restrict__ GBT)
{
    __shared__ float t[32][33];
    const int which = blockIdx.z;
    const float* src = which ? GB : GA;
    const float* scv = which ? isA : isM;
    unsigned short* dst = which ? GBT : GAT;
    const int r0 = blockIdx.x * 32;   // K (=R) dim
    const int n0 = blockIdx.y * 32;   // N (=256) dim
    const int tx = threadIdx.x & 31, ty = threadIdx.x >> 5;
    #pragma unroll
    for (int q = 0; q < 4; q++) {
        int rr = ty + q * 8;
        t[rr][tx] = scv[r0 + rr] * src[(size_t)(r0 + rr) * 256 + n0 + tx];
    }
    __syncthreads();
    #pragma unroll
    for (int q = 0; q < 4; q++) {
        int nn = ty + q * 8;
        dst[(size_t)(n0 + nn) * R_DIM + r0 + tx] = f2bf(t[tx][nn]);
    }
}

// Prep 2: cast w (A x M, row-major) to bf16 unchanged (already N x K layout).
__global__ __launch_bounds__(256) void prep_cast_w(
    const float* __restrict__ w, unsigned short* __restrict__ wb)
{
    int i = blockIdx.x * 256 + threadIdx.x;
    wb[i] = f2bf(w[i]);
}

// ---------------------------------------------------------------------------
// Main fused kernel: one block per batch row.
//   phase 1: build val row in LDS (+ write mclip bf16)
//   phase 2: per rule soft-min over H gathered vals, g = g_body*gate,
//            write g (bf16), accumulate exp(BETA*g) into per-head LDS bins
//            for heads < 256 (only those feed the output)
//   phase 3: write val_new columns of out
// ---------------------------------------------------------------------------
__global__ __launch_bounds__(256) void main_fused(
    const float* __restrict__ M_minus, const float* __restrict__ amask,
    const float* __restrict__ gate,    const float* __restrict__ bmask,
    const int* __restrict__ bidx,      const int* __restrict__ hidx,
    unsigned short* __restrict__ g_bf, unsigned short* __restrict__ mclip_bf,
    float* __restrict__ outp)
{
    __shared__ float vrow[P_DIM];
    __shared__ float shead[M_DIM];
    const int b = blockIdx.x;
    const int tid = threadIdx.x;

    shead[tid] = 0.0f;
    #pragma unroll
    for (int it = 0; it < P_DIM / 256; it++) {
        int p = tid + it * 256;
        float am = amask[(size_t)b * P_DIM + p];
        float v;
        if (p < M_DIM) {
            float mc = M_minus[(size_t)b * M_DIM + p];
            mc = fminf(fmaxf(mc, 0.0f), 1.0f);
            mclip_bf[(size_t)b * M_DIM + p] = f2bf(mc);
            v = fmaxf(mc, am);
        } else {
            v = am;
        }
        vrow[p] = v;
    }
    __syncthreads();

    for (int it = 0; it < R_DIM / 256; it++) {
        int rr = tid + it * 256;
        const int*   bi = bidx + rr * H_DIM;
        const float* bm = bmask + rr * H_DIM;
        float vv[H_DIM];
        float vmin = 1.0e4f;
        #pragma unroll
        for (int h = 0; h < H_DIM; h++) {
            float bv = vrow[bi[h]];
            float x = (bm[h] > 0.0f) ? bv : 1.0e4f;
            vv[h] = x;
            vmin = fminf(vmin, x);
        }
        float s = 0.0f;
        #pragma unroll
        for (int h = 0; h < H_DIM; h++) s += __expf((vmin - vv[h]) * 10.0f); // 1/TAU
        float gb = vmin - 0.1f * __logf(s);       // soft-min
        float g = gb * gate[(size_t)b * R_DIM + rr];
        g_bf[(size_t)b * R_DIM + rr] = f2bf(g);
        int hh = hidx[rr];
        if (hh < M_DIM) atomicAdd(&shead[hh], __expf(5.0f * g));  // BETA*g in [-0.9,5]
    }
    __syncthreads();

    #pragma unroll
    for (int it = 0; it < P_DIM / 256; it++) {
        int p = tid + it * 256;
        float v = vrow[p];
        if (p < M_DIM) {
            float s = shead[p];
            if (s > 0.0f) v = fmaxf(v, __logf(s) * 0.2f);   // /BETA
        }
        outp[(size_t)b * OUT_STRIDE + p] = v;
    }
}

// ---------------------------------------------------------------------------
// bf16 MFMA GEMM: C(MxN) = A(MxK) * Bt(NxK)^T, 64x64 tile, 4 waves, BK=64.
// EPI==0: main GEMM -> out[:, 2048+gn] = relu(acc) (+ aux for gn>=256)
// EPI==1: lam_ment  -> out[m*256+gn] = softplus(bias[gn] + acc)
// ---------------------------------------------------------------------------
template<int EPI>
__global__ __launch_bounds__(256) void gemm_bf16(
    const unsigned short* __restrict__ Ag,
    const unsigned short* __restrict__ Btg,
    float* __restrict__ outp,
    const float* __restrict__ aux,
    const float* __restrict__ bias,
    int K)
{
    __shared__ __align__(16) unsigned short Alds[64][72];
    __shared__ __align__(16) unsigned short Blds[64][72];
    const int m0 = blockIdx.x * 64, n0 = blockIdx.y * 64;
    const int tid = threadIdx.x;
    const int lane = tid & 63, wid = tid >> 6;
    const int wr = wid >> 1, wc = wid & 1;
    f32x4 acc[2][2] = {};
    const int sr = tid >> 3, scc = (tid & 7) * 8;

    for (int kt = 0; kt < K; kt += 64) {
        *(uint4*)&Alds[sr][scc]    = *(const uint4*)&Ag[(size_t)(m0 + sr) * K + kt + scc];
        *(uint4*)&Alds[sr+32][scc] = *(const uint4*)&Ag[(size_t)(m0 + sr + 32) * K + kt + scc];
        *(uint4*)&Blds[sr][scc]    = *(const uint4*)&Btg[(size_t)(n0 + sr) * K + kt + scc];
        *(uint4*)&Blds[sr+32][scc] = *(const uint4*)&Btg[(size_t)(n0 + sr + 32) * K + kt + scc];
        __syncthreads();
        #pragma unroll
        for (int ks = 0; ks < 64; ks += 32) {
            const int kr = ks + (lane >> 4) * 8;
            short8 a0 = *(const short8*)&Alds[wr*32 +      (lane & 15)][kr];
            short8 a1 = *(const short8*)&Alds[wr*32 + 16 + (lane & 15)][kr];
            short8 b0 = *(const short8*)&Blds[wc*32 +      (lane & 15)][kr];
            short8 b1 = *(const short8*)&Blds[wc*32 + 16 + (lane & 15)][kr];
            acc[0][0] = __builtin_amdgcn_mfma_f32_16x16x32_bf16(a0, b0, acc[0][0], 0, 0, 0);
            acc[0][1] = __builtin_amdgcn_mfma_f32_16x16x32_bf16(a0, b1, acc[0][1], 0, 0, 0);
            acc[1][0] = __builtin_amdgcn_mfma_f32_16x16x32_bf16(a1, b0, acc[1][0], 0, 0, 0);
            acc[1][1] = __builtin_amdgcn_mfma_f32_16x16x32_bf16(a1, b1, acc[1][1], 0, 0, 0);
        }
        __syncthreads();
    }

    const int rbase = (lane >> 4) * 4;
    const int cbase = lane & 15;
    #pragma unroll
    for (int i = 0; i < 2; i++) {
        #pragma unroll
        for (int j = 0; j < 2; j++) {
            const int gn = n0 + wc * 32 + j * 16 + cbase;
            #pragma unroll
            for (int q = 0; q < 4; q++) {
                const int gm = m0 + wr * 32 + i * 16 + rbase + q;
                float v = acc[i][j][q];
                if (EPI == 0) {
                    float o = fmaxf(v, 0.0f);
                    if (gn >= 256) o += aux[(size_t)gm * 256 + (gn - 256)];
                    outp[(size_t)gm * OUT_STRIDE + 2048 + gn] = o;
                } else {
                    float x = bias[gn] + v;
                    outp[(size_t)gm * 256 + gn] = (x > 20.0f) ? x : log1pf(__expf(x));
                }
            }
        }
    }
}

// ---------------------------------------------------------------------------
extern "C" void kernel_launch(void* const* d_in, const int* in_sizes, int n_in,
                              void* d_out, int out_size, void* d_ws, size_t ws_size,
                              hipStream_t stream)
{
    const float* M_minus = (const float*)d_in[0];
    const float* amask   = (const float*)d_in[1];
    const float* gate    = (const float*)d_in[2];
    const float* bmask   = (const float*)d_in[3];
    const float* isM     = (const float*)d_in[4];
    const float* isA     = (const float*)d_in[5];
    const float* GA      = (const float*)d_in[6];
    const float* GB      = (const float*)d_in[7];
    const float* bvec    = (const float*)d_in[8];
    const float* w       = (const float*)d_in[9];
    const int*   bidx    = (const int*)d_in[10];
    const int*   hidx    = (const int*)d_in[11];
    float* outp = (float*)d_out;

    char* ws = (char*)d_ws;
    unsigned short* g_bf   = (unsigned short*)(ws + 0);         // 16 MiB
    unsigned short* GAT    = (unsigned short*)(ws + 16777216);  // 2 MiB
    unsigned short* GBT    = (unsigned short*)(ws + 18874368);  // 2 MiB (contiguous after GAT)
    unsigned short* w_bf   = (unsigned short*)(ws + 20971520);  // 128 KiB
    unsigned short* mclip  = (unsigned short*)(ws + 21102592);  // 1 MiB
    float*          lam_ws = (float*)(ws + 22151168);           // 2 MiB

    prep_transpose<<<dim3(R_DIM / 32, 256 / 32, 2), dim3(256), 0, stream>>>(
        GA, GB, isM, isA, GAT, GBT);
    prep_cast_w<<<dim3((A_DIM * M_DIM) / 256), dim3(256), 0, stream>>>(w, w_bf);
    main_fused<<<dim3(B_DIM), dim3(256), 0, stream>>>(
        M_minus, amask, gate, bmask, bidx, hidx, g_bf, mclip, outp);
    // lam_ment = softplus(b + Mclip @ w^T) -> lam_ws
    gemm_bf16<1><<<dim3(B_DIM / 64, A_DIM / 64), dim3(256), 0, stream>>>(
        mclip, w_bf, lam_ws, nullptr, bvec, M_DIM);
    // [S | lam_logic] = relu(g @ [GAT|GBT]^T), lam cols += lam_ws
    gemm_bf16<0><<<dim3(B_DIM / 64, 512 / 64), dim3(256), 0, stream>>>(
        g_bf, GAT, outp, lam_ws, nullptr, R_DIM);
}

// Round 2
// 68.635 us; speedup vs baseline: 2.1874x; 2.1874x over previous
//
#include <hip/hip_runtime.h>

typedef __attribute__((ext_vector_type(8))) short short8;
typedef __attribute__((ext_vector_type(4))) float f32x4;

#define B_DIM 2048
#define P_DIM 2048
#define R_DIM 4096
#define H_DIM 6
#define M_DIM 256
#define A_DIM 256
#define OUT_STRIDE 2560   // P + M + A

static __device__ __forceinline__ unsigned short f2bf(float f) {
    unsigned u = __builtin_bit_cast(unsigned, f);
    u += 0x7fffu + ((u >> 16) & 1u);          // round-to-nearest-even
    return (unsigned short)(u >> 16);
}

// ---------------------------------------------------------------------------
// Prep 1: GAT[n][k] = bf16(is_toM[k] * Gamma_AtoM[k][n]) (and GBT from is_toA,
// Gamma_MtoA). 32x32 LDS tile transpose. grid (K/32, N/32, 2), block 256.
// ---------------------------------------------------------------------------
__global__ __launch_bounds__(256) void prep_transpose(
    const float* __restrict__ GA, const float* __restrict__ GB,
    const float* __restrict__ isM, const float* __restrict__ isA,
    unsigned short* __restrict__ GAT, unsigned short* __restrict__ GBT)
{
    __shared__ float t[32][33];
    const int which = blockIdx.z;
    const float* src = which ? GB : GA;
    const float* scv = which ? isA : isM;
    unsigned short* dst = which ? GBT : GAT;
    const int r0 = blockIdx.x * 32;   // K (=R) dim
    const int n0 = blockIdx.y * 32;   // N (=256) dim
    const int tx = threadIdx.x & 31, ty = threadIdx.x >> 5;
    #pragma unroll
    for (int q = 0; q < 4; q++) {
        int rr = ty + q * 8;
        t[rr][tx] = scv[r0 + rr] * src[(size_t)(r0 + rr) * 256 + n0 + tx];
    }
    __syncthreads();
    #pragma unroll
    for (int q = 0; q < 4; q++) {
        int nn = ty + q * 8;
        dst[(size_t)(n0 + nn) * R_DIM + r0 + tx] = f2bf(t[tx][nn]);
    }
}

// Prep 2: cast w (A x M, row-major) to bf16 unchanged (already N x K layout).
__global__ __launch_bounds__(256) void prep_cast_w(
    const float* __restrict__ w, unsigned short* __restrict__ wb)
{
    int i = blockIdx.x * 256 + threadIdx.x;
    wb[i] = f2bf(w[i]);
}

// ---------------------------------------------------------------------------
// Main fused kernel: one block per batch row.
// ---------------------------------------------------------------------------
__global__ __launch_bounds__(256) void main_fused(
    const float* __restrict__ M_minus, const float* __restrict__ amask,
    const float* __restrict__ gate,    const float* __restrict__ bmask,
    const int* __restrict__ bidx,      const int* __restrict__ hidx,
    unsigned short* __restrict__ g_bf, unsigned short* __restrict__ mclip_bf,
    float* __restrict__ outp)
{
    __shared__ float vrow[P_DIM];
    __shared__ float shead[M_DIM];
    const int b = blockIdx.x;
    const int tid = threadIdx.x;

    shead[tid] = 0.0f;
    const float4* am4 = (const float4*)(amask + (size_t)b * P_DIM);
    const float4* mm4 = (const float4*)(M_minus + (size_t)b * M_DIM);
    #pragma unroll
    for (int it = 0; it < 2; it++) {
        int c = tid + it * 256;           // float4 index; p = 4c
        float4 v = am4[c];
        if (c < M_DIM / 4) {
            float4 m = mm4[c];
            float mc0 = fminf(fmaxf(m.x, 0.0f), 1.0f);
            float mc1 = fminf(fmaxf(m.y, 0.0f), 1.0f);
            float mc2 = fminf(fmaxf(m.z, 0.0f), 1.0f);
            float mc3 = fminf(fmaxf(m.w, 0.0f), 1.0f);
            ushort4 mb; mb.x = f2bf(mc0); mb.y = f2bf(mc1); mb.z = f2bf(mc2); mb.w = f2bf(mc3);
            ((ushort4*)(mclip_bf + (size_t)b * M_DIM))[c] = mb;
            v.x = fmaxf(mc0, v.x); v.y = fmaxf(mc1, v.y);
            v.z = fmaxf(mc2, v.z); v.w = fmaxf(mc3, v.w);
        }
        ((float4*)vrow)[c] = v;
    }
    __syncthreads();

    #pragma unroll 2
    for (int it = 0; it < R_DIM / 256; it++) {
        int rr = tid + it * 256;
        const int2*   bi2 = (const int2*)bidx + rr * 3;
        const float2* bm2 = (const float2*)bmask + rr * 3;
        int2 i01 = bi2[0], i23 = bi2[1], i45 = bi2[2];
        float2 m01 = bm2[0], m23 = bm2[1], m45 = bm2[2];
        int   bi[H_DIM] = { i01.x, i01.y, i23.x, i23.y, i45.x, i45.y };
        float bm[H_DIM] = { m01.x, m01.y, m23.x, m23.y, m45.x, m45.y };
        float vv[H_DIM];
        float vmin = 1.0e4f;
        #pragma unroll
        for (int h = 0; h < H_DIM; h++) {
            float bv = vrow[bi[h]];
            float x = (bm[h] > 0.0f) ? bv : 1.0e4f;
            vv[h] = x;
            vmin = fminf(vmin, x);
        }
        float s = 0.0f;
        #pragma unroll
        for (int h = 0; h < H_DIM; h++) s += __expf((vmin - vv[h]) * 10.0f); // 1/TAU
        float gb = vmin - 0.1f * __logf(s);       // soft-min
        float g = gb * gate[(size_t)b * R_DIM + rr];
        g_bf[(size_t)b * R_DIM + rr] = f2bf(g);
        int hh = hidx[rr];
        if (hh < M_DIM) atomicAdd(&shead[hh], __expf(5.0f * g));  // BETA*g in [-0.9,5]
    }
    __syncthreads();

    float* orow = outp + (size_t)b * OUT_STRIDE;
    #pragma unroll
    for (int it = 0; it < 2; it++) {
        int c = tid + it * 256;
        float4 v = ((const float4*)vrow)[c];
        if (c < M_DIM / 4) {
            int p = c * 4;
            float s0 = shead[p], s1 = shead[p+1], s2 = shead[p+2], s3 = shead[p+3];
            if (s0 > 0.0f) v.x = fmaxf(v.x, __logf(s0) * 0.2f);
            if (s1 > 0.0f) v.y = fmaxf(v.y, __logf(s1) * 0.2f);
            if (s2 > 0.0f) v.z = fmaxf(v.z, __logf(s2) * 0.2f);
            if (s3 > 0.0f) v.w = fmaxf(v.w, __logf(s3) * 0.2f);
        }
        ((float4*)orow)[c] = v;
    }
}

// ---------------------------------------------------------------------------
// Split-K bf16 MFMA GEMM, 64x64 tile, 4 waves, BK=64, global_load_lds(16B)
// staging with XOR-swizzled source + reads (linear LDS dest).
// part[z][m][n] f32 partials; z = blockIdx.z over K-chunks of K/gridDim.z.
// ---------------------------------------------------------------------------
__device__ __forceinline__ void stage16(unsigned short* lds,
                                        const unsigned short* gsrc,
                                        int K, int c)
{
    const int row = c >> 3, slot = c & 7;
    const int k8 = slot ^ (row & 7);      // logical 16B-chunk living at this slot
    __builtin_amdgcn_global_load_lds(
        (const __attribute__((address_space(1))) void*)(gsrc + (size_t)row * K + k8 * 8),
        (__attribute__((address_space(3))) void*)(lds + c * 8), 16, 0, 0);
}

__global__ __launch_bounds__(256) void gemm_splitk(
    const unsigned short* __restrict__ Ag,
    const unsigned short* __restrict__ Btg,
    float* __restrict__ part, int K, int NS)
{
    __shared__ __align__(16) unsigned short Alds[64 * 64];
    __shared__ __align__(16) unsigned short Blds[64 * 64];
    const int Kc = K / gridDim.z;
    const int k0 = blockIdx.z * Kc;
    part += (size_t)blockIdx.z * B_DIM * NS;
    const int m0 = blockIdx.x * 64, n0 = blockIdx.y * 64;
    const int tid = threadIdx.x;
    const int lane = tid & 63, wid = tid >> 6;
    const int wr = wid >> 1, wc = wid & 1;
    f32x4 acc[2][2] = {};

    for (int kt = 0; kt < Kc; kt += 64) {
        const unsigned short* Ab = Ag  + (size_t)m0 * K + k0 + kt;
        const unsigned short* Bb = Btg + (size_t)n0 * K + k0 + kt;
        stage16(Alds, Ab, K, tid);
        stage16(Alds, Ab, K, tid + 256);
        stage16(Blds, Bb, K, tid);
        stage16(Blds, Bb, K, tid + 256);
        __syncthreads();
        #pragma unroll
        for (int ks = 0; ks < 64; ks += 32) {
            const int k8 = (ks >> 3) + (lane >> 4);   // kr>>3
            const int r0a = wr * 32 + (lane & 15);
            const int r0b = wc * 32 + (lane & 15);
            short8 a0 = *(const short8*)&Alds[(r0a)      * 64 + ((k8 ^ (r0a & 7)) << 3)];
            short8 a1 = *(const short8*)&Alds[(r0a + 16) * 64 + ((k8 ^ (r0a & 7)) << 3)];
            short8 b0 = *(const short8*)&Blds[(r0b)      * 64 + ((k8 ^ (r0b & 7)) << 3)];
            short8 b1 = *(const short8*)&Blds[(r0b + 16) * 64 + ((k8 ^ (r0b & 7)) << 3)];
            acc[0][0] = __builtin_amdgcn_mfma_f32_16x16x32_bf16(a0, b0, acc[0][0], 0, 0, 0);
            acc[0][1] = __builtin_amdgcn_mfma_f32_16x16x32_bf16(a0, b1, acc[0][1], 0, 0, 0);
            acc[1][0] = __builtin_amdgcn_mfma_f32_16x16x32_bf16(a1, b0, acc[1][0], 0, 0, 0);
            acc[1][1] = __builtin_amdgcn_mfma_f32_16x16x32_bf16(a1, b1, acc[1][1], 0, 0, 0);
        }
        __syncthreads();
    }

    const int rbase = (lane >> 4) * 4;
    const int cbase = lane & 15;
    #pragma unroll
    for (int i = 0; i < 2; i++) {
        #pragma unroll
        for (int j = 0; j < 2; j++) {
            const int gn = n0 + wc * 32 + j * 16 + cbase;
            #pragma unroll
            for (int q = 0; q < 4; q++) {
                const int gm = m0 + wr * 32 + i * 16 + rbase + q;
                part[(size_t)gm * NS + gn] = acc[i][j][q];
            }
        }
    }
}

// ---------------------------------------------------------------------------
// Epilogue: sum split-K partials; relu(main); for lam cols add
// softplus(b + lam_ment). Writes out[:, 2048:2560]. float4 over 2048x512.
// ---------------------------------------------------------------------------
__global__ __launch_bounds__(256) void epilogue(
    const float* __restrict__ mainpart, const float* __restrict__ lampart,
    const float* __restrict__ bvec, float* __restrict__ outp)
{
    const int idx = blockIdx.x * 256 + threadIdx.x;   // over 2048*128
    const int m = idx >> 7, n4 = idx & 127;
    const size_t mb = (size_t)m * 128 + n4;           // float4 units (NS=512)
    const size_t zs = (size_t)B_DIM * 128;
    float4 s = ((const float4*)mainpart)[mb];
    #pragma unroll
    for (int z = 1; z < 4; z++) {
        float4 t = ((const float4*)mainpart)[mb + z * zs];
        s.x += t.x; s.y += t.y; s.z += t.z; s.w += t.w;
    }
    s.x = fmaxf(s.x, 0.0f); s.y = fmaxf(s.y, 0.0f);
    s.z = fmaxf(s.z, 0.0f); s.w = fmaxf(s.w, 0.0f);
    if (n4 >= 64) {
        const int na = n4 - 64;                       // float4 idx in 256-col lam
        const size_t lb = (size_t)m * 64 + na;
        float4 l0 = ((const float4*)lampart)[lb];
        float4 l1 = ((const float4*)lampart)[lb + (size_t)B_DIM * 64];
        float4 bb = ((const float4*)bvec)[na];
        float x0 = bb.x + l0.x + l1.x, x1 = bb.y + l0.y + l1.y;
        float x2 = bb.z + l0.z + l1.z, x3 = bb.w + l0.w + l1.w;
        s.x += (x0 > 20.0f) ? x0 : log1pf(__expf(x0));
        s.y += (x1 > 20.0f) ? x1 : log1pf(__expf(x1));
        s.z += (x2 > 20.0f) ? x2 : log1pf(__expf(x2));
        s.w += (x3 > 20.0f) ? x3 : log1pf(__expf(x3));
    }
    ((float4*)(outp + (size_t)m * OUT_STRIDE + 2048))[n4] = s;
}

// ---------------------------------------------------------------------------
extern "C" void kernel_launch(void* const* d_in, const int* in_sizes, int n_in,
                              void* d_out, int out_size, void* d_ws, size_t ws_size,
                              hipStream_t stream)
{
    const float* M_minus = (const float*)d_in[0];
    const float* amask   = (const float*)d_in[1];
    const float* gate    = (const float*)d_in[2];
    const float* bmask   = (const float*)d_in[3];
    const float* isM     = (const float*)d_in[4];
    const float* isA     = (const float*)d_in[5];
    const float* GA      = (const float*)d_in[6];
    const float* GB      = (const float*)d_in[7];
    const float* bvec    = (const float*)d_in[8];
    const float* w       = (const float*)d_in[9];
    const int*   bidx    = (const int*)d_in[10];
    const int*   hidx    = (const int*)d_in[11];
    float* outp = (float*)d_out;

    char* ws = (char*)d_ws;
    unsigned short* g_bf   = (unsigned short*)(ws + 0);          // 16 MiB
    unsigned short* GAT    = (unsigned short*)(ws + (16u<<20));  // 2 MiB
    unsigned short* GBT    = (unsigned short*)(ws + (18u<<20));  // 2 MiB (contiguous after GAT)
    unsigned short* w_bf   = (unsigned short*)(ws + (20u<<20));  // 128 KiB
    unsigned short* mclip  = (unsigned short*)(ws + (21u<<20));  // 1 MiB
    float*          mainp  = (float*)(ws + (22u<<20));           // 4 x 4 MiB
    float*          lamp   = (float*)(ws + (38u<<20));           // 2 x 2 MiB

    prep_transpose<<<dim3(R_DIM / 32, 256 / 32, 2), dim3(256), 0, stream>>>(
        GA, GB, isM, isA, GAT, GBT);
    prep_cast_w<<<dim3((A_DIM * M_DIM) / 256), dim3(256), 0, stream>>>(w, w_bf);
    main_fused<<<dim3(B_DIM), dim3(256), 0, stream>>>(
        M_minus, amask, gate, bmask, bidx, hidx, g_bf, mclip, outp);
    // lam_ment partials: Mclip @ w^T, K=256 split 2 -> 256 blocks
    gemm_splitk<<<dim3(B_DIM / 64, A_DIM / 64, 2), dim3(256), 0, stream>>>(
        mclip, w_bf, lamp, M_DIM, A_DIM);
    // [S | lam_logic] partials: g @ [GAT|GBT]^T, K=4096 split 4 -> 1024 blocks
    gemm_splitk<<<dim3(B_DIM / 64, 512 / 64, 4), dim3(256), 0, stream>>>(
        g_bf, GAT, mainp, R_DIM, 512);
    epilogue<<<dim3((B_DIM * 128) / 256), dim3(256), 0, stream>>>(
        mainp, lamp, bvec, outp);
}

// Round 3
// 63.795 us; speedup vs baseline: 2.3533x; 1.0759x over previous
//
#include <hip/hip_runtime.h>

typedef __attribute__((ext_vector_type(8))) short short8;
typedef __attribute__((ext_vector_type(4))) float f32x4;

#define B_DIM 2048
#define P_DIM 2048
#define R_DIM 4096
#define H_DIM 6
#define M_DIM 256
#define A_DIM 256
#define OUT_STRIDE 2560   // P + M + A
#define NB 4              // batch rows per main_fused block

static __device__ __forceinline__ unsigned short f2bf(float f) {
    unsigned u = __builtin_bit_cast(unsigned, f);
    u += 0x7fffu + ((u >> 16) & 1u);          // round-to-nearest-even
    return (unsigned short)(u >> 16);
}

// ---------------------------------------------------------------------------
// Prep 1: GAT[n][k] = bf16(is_toM[k] * Gamma_AtoM[k][n]) (and GBT from is_toA,
// Gamma_MtoA). 32x32 LDS tile transpose. grid (K/32, N/32, 2), block 256.
// ---------------------------------------------------------------------------
__global__ __launch_bounds__(256) void prep_transpose(
    const float* __restrict__ GA, const float* __restrict__ GB,
    const float* __restrict__ isM, const float* __restrict__ isA,
    unsigned short* __restrict__ GAT, unsigned short* __restrict__ GBT)
{
    __shared__ float t[32][33];
    const int which = blockIdx.z;
    const float* src = which ? GB : GA;
    const float* scv = which ? isA : isM;
    unsigned short* dst = which ? GBT : GAT;
    const int r0 = blockIdx.x * 32;   // K (=R) dim
    const int n0 = blockIdx.y * 32;   // N (=256) dim
    const int tx = threadIdx.x & 31, ty = threadIdx.x >> 5;
    #pragma unroll
    for (int q = 0; q < 4; q++) {
        int rr = ty + q * 8;
        t[rr][tx] = scv[r0 + rr] * src[(size_t)(r0 + rr) * 256 + n0 + tx];
    }
    __syncthreads();
    #pragma unroll
    for (int q = 0; q < 4; q++) {
        int nn = ty + q * 8;
        dst[(size_t)(n0 + nn) * R_DIM + r0 + tx] = f2bf(t[tx][nn]);
    }
}

// Prep 2: cast w (A x M, row-major) to bf16 unchanged (already N x K layout).
__global__ __launch_bounds__(256) void prep_cast_w(
    const float* __restrict__ w, unsigned short* __restrict__ wb)
{
    int i = blockIdx.x * 256 + threadIdx.x;
    wb[i] = f2bf(w[i]);
}

// ---------------------------------------------------------------------------
// Main fused kernel: NB batch rows per block, 512 threads.
// Rule indices/masks loaded ONCE per rule, reused across NB rows (L2 traffic
// /NB, and NB independent gather+transcendental chains per rule for MLP).
// ---------------------------------------------------------------------------
__global__ __launch_bounds__(512) void main_fused(
    const float* __restrict__ M_minus, const float* __restrict__ amask,
    const float* __restrict__ gate,    const float* __restrict__ bmask,
    const int* __restrict__ bidx,      const int* __restrict__ hidx,
    unsigned short* __restrict__ g_bf, unsigned short* __restrict__ mclip_bf,
    float* __restrict__ outp)
{
    __shared__ float vrow[NB][P_DIM];
    __shared__ float shead[NB][M_DIM];
    const int b0 = blockIdx.x * NB;
    const int tid = threadIdx.x;

    if (tid < M_DIM) {
        #pragma unroll
        for (int r = 0; r < NB; r++) shead[r][tid] = 0.0f;
    }
    // phase 1: build NB val rows (one float4 per thread per row)
    #pragma unroll
    for (int r = 0; r < NB; r++) {
        const int c = tid;                            // float4 index, 512 = P/4
        float4 v = ((const float4*)(amask + (size_t)(b0 + r) * P_DIM))[c];
        if (c < M_DIM / 4) {
            float4 m = ((const float4*)(M_minus + (size_t)(b0 + r) * M_DIM))[c];
            float mc0 = fminf(fmaxf(m.x, 0.0f), 1.0f);
            float mc1 = fminf(fmaxf(m.y, 0.0f), 1.0f);
            float mc2 = fminf(fmaxf(m.z, 0.0f), 1.0f);
            float mc3 = fminf(fmaxf(m.w, 0.0f), 1.0f);
            ushort4 mb; mb.x = f2bf(mc0); mb.y = f2bf(mc1); mb.z = f2bf(mc2); mb.w = f2bf(mc3);
            ((ushort4*)(mclip_bf + (size_t)(b0 + r) * M_DIM))[c] = mb;
            v.x = fmaxf(mc0, v.x); v.y = fmaxf(mc1, v.y);
            v.z = fmaxf(mc2, v.z); v.w = fmaxf(mc3, v.w);
        }
        ((float4*)vrow[r])[c] = v;
    }
    __syncthreads();

    // phase 2: rules. 4096/512 = 8 iters; indices shared across NB rows.
    for (int it = 0; it < R_DIM / 512; it++) {
        const int rr = tid + it * 512;
        const int2*   bi2 = (const int2*)bidx + rr * 3;
        const float2* bm2 = (const float2*)bmask + rr * 3;
        int2 i01 = bi2[0], i23 = bi2[1], i45 = bi2[2];
        float2 m01 = bm2[0], m23 = bm2[1], m45 = bm2[2];
        const int   bi[H_DIM] = { i01.x, i01.y, i23.x, i23.y, i45.x, i45.y };
        const float bm[H_DIM] = { m01.x, m01.y, m23.x, m23.y, m45.x, m45.y };
        const int hh = hidx[rr];
        float gv[NB];
        #pragma unroll
        for (int r = 0; r < NB; r++)
            gv[r] = gate[(size_t)(b0 + r) * R_DIM + rr];
        #pragma unroll
        for (int r = 0; r < NB; r++) {
            float vv[H_DIM];
            float vmin = 1.0e4f;
            #pragma unroll
            for (int h = 0; h < H_DIM; h++) {
                float x = (bm[h] > 0.0f) ? vrow[r][bi[h]] : 1.0e4f;
                vv[h] = x;
                vmin = fminf(vmin, x);
            }
            float s = 0.0f;
            #pragma unroll
            for (int h = 0; h < H_DIM; h++) s += __expf((vmin - vv[h]) * 10.0f); // 1/TAU
            float g = (vmin - 0.1f * __logf(s)) * gv[r];
            g_bf[(size_t)(b0 + r) * R_DIM + rr] = f2bf(g);
            if (hh < M_DIM) atomicAdd(&shead[r][hh], __expf(5.0f * g));  // BETA*g in [-0.9,5]
        }
    }
    __syncthreads();

    // phase 3: val_new columns of out
    #pragma unroll
    for (int r = 0; r < NB; r++) {
        const int c = tid;
        float4 v = ((const float4*)vrow[r])[c];
        if (c < M_DIM / 4) {
            int p = c * 4;
            float s0 = shead[r][p], s1 = shead[r][p+1], s2 = shead[r][p+2], s3 = shead[r][p+3];
            if (s0 > 0.0f) v.x = fmaxf(v.x, __logf(s0) * 0.2f);
            if (s1 > 0.0f) v.y = fmaxf(v.y, __logf(s1) * 0.2f);
            if (s2 > 0.0f) v.z = fmaxf(v.z, __logf(s2) * 0.2f);
            if (s3 > 0.0f) v.w = fmaxf(v.w, __logf(s3) * 0.2f);
        }
        ((float4*)(outp + (size_t)(b0 + r) * OUT_STRIDE))[c] = v;
    }
}

// ---------------------------------------------------------------------------
// Split-K bf16 MFMA GEMM, 64x64 tile, 4 waves, BK=64, global_load_lds(16B)
// staging with XOR-swizzled source + reads (linear LDS dest).
// part[z][m][n] f32 partials; z = blockIdx.z over K-chunks of K/gridDim.z.
// ---------------------------------------------------------------------------
__device__ __forceinline__ void stage16(unsigned short* lds,
                                        const unsigned short* gsrc,
                                        int K, int c)
{
    const int row = c >> 3, slot = c & 7;
    const int k8 = slot ^ (row & 7);      // logical 16B-chunk living at this slot
    __builtin_amdgcn_global_load_lds(
        (const __attribute__((address_space(1))) void*)(gsrc + (size_t)row * K + k8 * 8),
        (__attribute__((address_space(3))) void*)(lds + c * 8), 16, 0, 0);
}

__global__ __launch_bounds__(256) void gemm_splitk(
    const unsigned short* __restrict__ Ag,
    const unsigned short* __restrict__ Btg,
    float* __restrict__ part, int K, int NS)
{
    __shared__ __align__(16) unsigned short Alds[64 * 64];
    __shared__ __align__(16) unsigned short Blds[64 * 64];
    const int Kc = K / gridDim.z;
    const int k0 = blockIdx.z * Kc;
    part += (size_t)blockIdx.z * B_DIM * NS;
    const int m0 = blockIdx.x * 64, n0 = blockIdx.y * 64;
    const int tid = threadIdx.x;
    const int lane = tid & 63, wid = tid >> 6;
    const int wr = wid >> 1, wc = wid & 1;
    f32x4 acc[2][2] = {};

    for (int kt = 0; kt < Kc; kt += 64) {
        const unsigned short* Ab = Ag  + (size_t)m0 * K + k0 + kt;
        const unsigned short* Bb = Btg + (size_t)n0 * K + k0 + kt;
        stage16(Alds, Ab, K, tid);
        stage16(Alds, Ab, K, tid + 256);
        stage16(Blds, Bb, K, tid);
        stage16(Blds, Bb, K, tid + 256);
        __syncthreads();
        #pragma unroll
        for (int ks = 0; ks < 64; ks += 32) {
            const int k8 = (ks >> 3) + (lane >> 4);   // kr>>3
            const int r0a = wr * 32 + (lane & 15);
            const int r0b = wc * 32 + (lane & 15);
            short8 a0 = *(const short8*)&Alds[(r0a)      * 64 + ((k8 ^ (r0a & 7)) << 3)];
            short8 a1 = *(const short8*)&Alds[(r0a + 16) * 64 + ((k8 ^ (r0a & 7)) << 3)];
            short8 b0 = *(const short8*)&Blds[(r0b)      * 64 + ((k8 ^ (r0b & 7)) << 3)];
            short8 b1 = *(const short8*)&Blds[(r0b + 16) * 64 + ((k8 ^ (r0b & 7)) << 3)];
            acc[0][0] = __builtin_amdgcn_mfma_f32_16x16x32_bf16(a0, b0, acc[0][0], 0, 0, 0);
            acc[0][1] = __builtin_amdgcn_mfma_f32_16x16x32_bf16(a0, b1, acc[0][1], 0, 0, 0);
            acc[1][0] = __builtin_amdgcn_mfma_f32_16x16x32_bf16(a1, b0, acc[1][0], 0, 0, 0);
            acc[1][1] = __builtin_amdgcn_mfma_f32_16x16x32_bf16(a1, b1, acc[1][1], 0, 0, 0);
        }
        __syncthreads();
    }

    const int rbase = (lane >> 4) * 4;
    const int cbase = lane & 15;
    #pragma unroll
    for (int i = 0; i < 2; i++) {
        #pragma unroll
        for (int j = 0; j < 2; j++) {
            const int gn = n0 + wc * 32 + j * 16 + cbase;
            #pragma unroll
            for (int q = 0; q < 4; q++) {
                const int gm = m0 + wr * 32 + i * 16 + rbase + q;
                part[(size_t)gm * NS + gn] = acc[i][j][q];
            }
        }
    }
}

// ---------------------------------------------------------------------------
// Epilogue: sum split-K partials; relu(main); for lam cols add
// softplus(b + lam_ment). Writes out[:, 2048:2560]. float4 over 2048x512.
// ---------------------------------------------------------------------------
__global__ __launch_bounds__(256) void epilogue(
    const float* __restrict__ mainpart, const float* __restrict__ lampart,
    const float* __restrict__ bvec, float* __restrict__ outp)
{
    const int idx = blockIdx.x * 256 + threadIdx.x;   // over 2048*128
    const int m = idx >> 7, n4 = idx & 127;
    const size_t mb = (size_t)m * 128 + n4;           // float4 units (NS=512)
    const size_t zs = (size_t)B_DIM * 128;
    float4 s = ((const float4*)mainpart)[mb];
    #pragma unroll
    for (int z = 1; z < 4; z++) {
        float4 t = ((const float4*)mainpart)[mb + z * zs];
        s.x += t.x; s.y += t.y; s.z += t.z; s.w += t.w;
    }
    s.x = fmaxf(s.x, 0.0f); s.y = fmaxf(s.y, 0.0f);
    s.z = fmaxf(s.z, 0.0f); s.w = fmaxf(s.w, 0.0f);
    if (n4 >= 64) {
        const int na = n4 - 64;                       // float4 idx in 256-col lam
        const size_t lb = (size_t)m * 64 + na;
        float4 l0 = ((const float4*)lampart)[lb];
        float4 l1 = ((const float4*)lampart)[lb + (size_t)B_DIM * 64];
        float4 bb = ((const float4*)bvec)[na];
        float x0 = bb.x + l0.x + l1.x, x1 = bb.y + l0.y + l1.y;
        float x2 = bb.z + l0.z + l1.z, x3 = bb.w + l0.w + l1.w;
        s.x += (x0 > 20.0f) ? x0 : log1pf(__expf(x0));
        s.y += (x1 > 20.0f) ? x1 : log1pf(__expf(x1));
        s.z += (x2 > 20.0f) ? x2 : log1pf(__expf(x2));
        s.w += (x3 > 20.0f) ? x3 : log1pf(__expf(x3));
    }
    ((float4*)(outp + (size_t)m * OUT_STRIDE + 2048))[n4] = s;
}

// ---------------------------------------------------------------------------
extern "C" void kernel_launch(void* const* d_in, const int* in_sizes, int n_in,
                              void* d_out, int out_size, void* d_ws, size_t ws_size,
                              hipStream_t stream)
{
    const float* M_minus = (const float*)d_in[0];
    const float* amask   = (const float*)d_in[1];
    const float* gate    = (const float*)d_in[2];
    const float* bmask   = (const float*)d_in[3];
    const float* isM     = (const float*)d_in[4];
    const float* isA     = (const float*)d_in[5];
    const float* GA      = (const float*)d_in[6];
    const float* GB      = (const float*)d_in[7];
    const float* bvec    = (const float*)d_in[8];
    const float* w       = (const float*)d_in[9];
    const int*   bidx    = (const int*)d_in[10];
    const int*   hidx    = (const int*)d_in[11];
    float* outp = (float*)d_out;

    char* ws = (char*)d_ws;
    unsigned short* g_bf   = (unsigned short*)(ws + 0);          // 16 MiB
    unsigned short* GAT    = (unsigned short*)(ws + (16u<<20));  // 2 MiB
    unsigned short* GBT    = (unsigned short*)(ws + (18u<<20));  // 2 MiB (contiguous after GAT)
    unsigned short* w_bf   = (unsigned short*)(ws + (20u<<20));  // 128 KiB
    unsigned short* mclip  = (unsigned short*)(ws + (21u<<20));  // 1 MiB
    float*          mainp  = (float*)(ws + (22u<<20));           // 4 x 4 MiB
    float*          lamp   = (float*)(ws + (38u<<20));           // 2 x 2 MiB

    prep_transpose<<<dim3(R_DIM / 32, 256 / 32, 2), dim3(256), 0, stream>>>(
        GA, GB, isM, isA, GAT, GBT);
    prep_cast_w<<<dim3((A_DIM * M_DIM) / 256), dim3(256), 0, stream>>>(w, w_bf);
    main_fused<<<dim3(B_DIM / NB), dim3(512), 0, stream>>>(
        M_minus, amask, gate, bmask, bidx, hidx, g_bf, mclip, outp);
    // lam_ment partials: Mclip @ w^T, K=256 split 2 -> 256 blocks
    gemm_splitk<<<dim3(B_DIM / 64, A_DIM / 64, 2), dim3(256), 0, stream>>>(
        mclip, w_bf, lamp, M_DIM, A_DIM);
    // [S | lam_logic] partials: g @ [GAT|GBT]^T, K=4096 split 4 -> 1024 blocks
    gemm_splitk<<<dim3(B_DIM / 64, 512 / 64, 4), dim3(256), 0, stream>>>(
        g_bf, GAT, mainp, R_DIM, 512);
    epilogue<<<dim3((B_DIM * 128) / 256), dim3(256), 0, stream>>>(
        mainp, lamp, bvec, outp);
}

// Round 4
// 62.533 us; speedup vs baseline: 2.4008x; 1.0202x over previous
//
#include <hip/hip_runtime.h>

typedef __attribute__((ext_vector_type(8))) short short8;
typedef __attribute__((ext_vector_type(4))) float f32x4;

#define B_DIM 2048
#define P_DIM 2048
#define R_DIM 4096
#define H_DIM 6
#define M_DIM 256
#define A_DIM 256
#define OUT_STRIDE 2560   // P + M + A
#define NB 2              // batch rows per main_fused block

static __device__ __forceinline__ unsigned short f2bf(float f) {
    unsigned u = __builtin_bit_cast(unsigned, f);
    u += 0x7fffu + ((u >> 16) & 1u);          // round-to-nearest-even
    return (unsigned short)(u >> 16);
}

// ---------------------------------------------------------------------------
// Prep 1: GAT[n][k] = bf16(is_toM[k] * Gamma_AtoM[k][n]) (and GBT from is_toA,
// Gamma_MtoA). 32x32 LDS tile transpose. grid (K/32, N/32, 2), block 256.
// ---------------------------------------------------------------------------
__global__ __launch_bounds__(256) void prep_transpose(
    const float* __restrict__ GA, const float* __restrict__ GB,
    const float* __restrict__ isM, const float* __restrict__ isA,
    unsigned short* __restrict__ GAT, unsigned short* __restrict__ GBT)
{
    __shared__ float t[32][33];
    const int which = blockIdx.z;
    const float* src = which ? GB : GA;
    const float* scv = which ? isA : isM;
    unsigned short* dst = which ? GBT : GAT;
    const int r0 = blockIdx.x * 32;   // K (=R) dim
    const int n0 = blockIdx.y * 32;   // N (=256) dim
    const int tx = threadIdx.x & 31, ty = threadIdx.x >> 5;
    #pragma unroll
    for (int q = 0; q < 4; q++) {
        int rr = ty + q * 8;
        t[rr][tx] = scv[r0 + rr] * src[(size_t)(r0 + rr) * 256 + n0 + tx];
    }
    __syncthreads();
    #pragma unroll
    for (int q = 0; q < 4; q++) {
        int nn = ty + q * 8;
        dst[(size_t)(n0 + nn) * R_DIM + r0 + tx] = f2bf(t[tx][nn]);
    }
}

// Prep 2: cast w (A x M, row-major) to bf16 unchanged (already N x K layout).
__global__ __launch_bounds__(256) void prep_cast_w(
    const float* __restrict__ w, unsigned short* __restrict__ wb)
{
    int i = blockIdx.x * 256 + threadIdx.x;
    wb[i] = f2bf(w[i]);
}

// ---------------------------------------------------------------------------
// Main fused kernel: NB=2 batch rows per block, 512 threads, grid 1024
// (4 blocks/CU = 32 waves/CU). All 12 gathers issued before any compute.
// ---------------------------------------------------------------------------
__global__ __launch_bounds__(512, 4) void main_fused(
    const float* __restrict__ M_minus, const float* __restrict__ amask,
    const float* __restrict__ gate,    const float* __restrict__ bmask,
    const int* __restrict__ bidx,      const int* __restrict__ hidx,
    unsigned short* __restrict__ g_bf, unsigned short* __restrict__ mclip_bf,
    float* __restrict__ outp)
{
    __shared__ float vrow[NB][P_DIM];
    __shared__ float shead[NB][M_DIM];
    const int b0 = blockIdx.x * NB;
    const int tid = threadIdx.x;

    if (tid < M_DIM) {
        shead[0][tid] = 0.0f;
        shead[1][tid] = 0.0f;
    }
    // phase 1: build NB val rows (one float4 per thread per row; 512 = P/4)
    #pragma unroll
    for (int r = 0; r < NB; r++) {
        const int c = tid;
        float4 v = ((const float4*)(amask + (size_t)(b0 + r) * P_DIM))[c];
        if (c < M_DIM / 4) {
            float4 m = ((const float4*)(M_minus + (size_t)(b0 + r) * M_DIM))[c];
            float mc0 = fminf(fmaxf(m.x, 0.0f), 1.0f);
            float mc1 = fminf(fmaxf(m.y, 0.0f), 1.0f);
            float mc2 = fminf(fmaxf(m.z, 0.0f), 1.0f);
            float mc3 = fminf(fmaxf(m.w, 0.0f), 1.0f);
            ushort4 mb; mb.x = f2bf(mc0); mb.y = f2bf(mc1); mb.z = f2bf(mc2); mb.w = f2bf(mc3);
            ((ushort4*)(mclip_bf + (size_t)(b0 + r) * M_DIM))[c] = mb;
            v.x = fmaxf(mc0, v.x); v.y = fmaxf(mc1, v.y);
            v.z = fmaxf(mc2, v.z); v.w = fmaxf(mc3, v.w);
        }
        ((float4*)vrow[r])[c] = v;
    }
    __syncthreads();

    // phase 2: rules. 4096/512 = 8 iters; indices shared across NB rows.
    #pragma unroll 2
    for (int it = 0; it < R_DIM / 512; it++) {
        const int rr = tid + it * 512;
        const int2*   bi2 = (const int2*)bidx + rr * 3;
        const float2* bm2 = (const float2*)bmask + rr * 3;
        int2 i01 = bi2[0], i23 = bi2[1], i45 = bi2[2];
        float2 m01 = bm2[0], m23 = bm2[1], m45 = bm2[2];
        const int   bi[H_DIM] = { i01.x, i01.y, i23.x, i23.y, i45.x, i45.y };
        const float bm[H_DIM] = { m01.x, m01.y, m23.x, m23.y, m45.x, m45.y };
        const int hh = hidx[rr];
        float gv0 = gate[(size_t)b0 * R_DIM + rr];
        float gv1 = gate[(size_t)(b0 + 1) * R_DIM + rr];

        // issue ALL gathers before any use (wide independent ds_read burst)
        float x0[H_DIM], x1[H_DIM];
        #pragma unroll
        for (int h = 0; h < H_DIM; h++) {
            const int p = bi[h];
            x0[h] = vrow[0][p];
            x1[h] = vrow[1][p];
        }

        float vm0 = 1.0e4f, vm1 = 1.0e4f;
        #pragma unroll
        for (int h = 0; h < H_DIM; h++) {
            x0[h] = (bm[h] > 0.0f) ? x0[h] : 1.0e4f;
            x1[h] = (bm[h] > 0.0f) ? x1[h] : 1.0e4f;
            vm0 = fminf(vm0, x0[h]);
            vm1 = fminf(vm1, x1[h]);
        }
        float s0 = 0.0f, s1 = 0.0f;
        #pragma unroll
        for (int h = 0; h < H_DIM; h++) {
            s0 += __expf((vm0 - x0[h]) * 10.0f);   // 1/TAU
            s1 += __expf((vm1 - x1[h]) * 10.0f);
        }
        float gg0 = (vm0 - 0.1f * __logf(s0)) * gv0;
        float gg1 = (vm1 - 0.1f * __logf(s1)) * gv1;
        g_bf[(size_t)b0 * R_DIM + rr]       = f2bf(gg0);
        g_bf[(size_t)(b0 + 1) * R_DIM + rr] = f2bf(gg1);
        if (hh < M_DIM) {
            atomicAdd(&shead[0][hh], __expf(5.0f * gg0));   // BETA*g in [-0.9,5]
            atomicAdd(&shead[1][hh], __expf(5.0f * gg1));
        }
    }
    __syncthreads();

    // phase 3: val_new columns of out
    #pragma unroll
    for (int r = 0; r < NB; r++) {
        const int c = tid;
        float4 v = ((const float4*)vrow[r])[c];
        if (c < M_DIM / 4) {
            int p = c * 4;
            float s0 = shead[r][p], s1 = shead[r][p+1], s2 = shead[r][p+2], s3 = shead[r][p+3];
            if (s0 > 0.0f) v.x = fmaxf(v.x, __logf(s0) * 0.2f);
            if (s1 > 0.0f) v.y = fmaxf(v.y, __logf(s1) * 0.2f);
            if (s2 > 0.0f) v.z = fmaxf(v.z, __logf(s2) * 0.2f);
            if (s3 > 0.0f) v.w = fmaxf(v.w, __logf(s3) * 0.2f);
        }
        ((float4*)(outp + (size_t)(b0 + r) * OUT_STRIDE))[c] = v;
    }
}

// ---------------------------------------------------------------------------
// Split-K bf16 MFMA GEMM, 64x64 tile, 4 waves, BK=128, global_load_lds(16B)
// staging with XOR-swizzled source + reads (linear LDS dest).
// part[z][m][n] f32 partials; z = blockIdx.z over K-chunks of K/gridDim.z.
// ---------------------------------------------------------------------------
#define BKC 16   // 16B chunks per row (BK=128 bf16)
__device__ __forceinline__ void stage16(unsigned short* lds,
                                        const unsigned short* gsrc,
                                        int K, int c)
{
    const int row = c >> 4, slot = c & (BKC - 1);
    const int k8 = slot ^ (row & (BKC - 1));  // logical chunk at this slot
    __builtin_amdgcn_global_load_lds(
        (const __attribute__((address_space(1))) void*)(gsrc + (size_t)row * K + k8 * 8),
        (__attribute__((address_space(3))) void*)(lds + c * 8), 16, 0, 0);
}

__global__ __launch_bounds__(256) void gemm_splitk(
    const unsigned short* __restrict__ Ag,
    const unsigned short* __restrict__ Btg,
    float* __restrict__ part, int K, int NS)
{
    __shared__ __align__(16) unsigned short Alds[64 * 128];
    __shared__ __align__(16) unsigned short Blds[64 * 128];
    const int Kc = K / gridDim.z;
    const int k0 = blockIdx.z * Kc;
    part += (size_t)blockIdx.z * B_DIM * NS;
    const int m0 = blockIdx.x * 64, n0 = blockIdx.y * 64;
    const int tid = threadIdx.x;
    const int lane = tid & 63, wid = tid >> 6;
    const int wr = wid >> 1, wc = wid & 1;
    f32x4 acc[2][2] = {};

    for (int kt = 0; kt < Kc; kt += 128) {
        const unsigned short* Ab = Ag  + (size_t)m0 * K + k0 + kt;
        const unsigned short* Bb = Btg + (size_t)n0 * K + k0 + kt;
        #pragma unroll
        for (int q = 0; q < 4; q++) {
            stage16(Alds, Ab, K, tid + q * 256);
            stage16(Blds, Bb, K, tid + q * 256);
        }
        __syncthreads();
        #pragma unroll
        for (int ks = 0; ks < 4; ks++) {
            const int k8 = ks * 4 + (lane >> 4);
            const int r0a = wr * 32 + (lane & 15);
            const int r0b = wc * 32 + (lane & 15);
            const int sa = (k8 ^ (r0a & 15)) << 3;   // (r0a+16)&15 == r0a&15
            const int sb = (k8 ^ (r0b & 15)) << 3;
            short8 a0 = *(const short8*)&Alds[(r0a)      * 128 + sa];
            short8 a1 = *(const short8*)&Alds[(r0a + 16) * 128 + sa];
            short8 b0 = *(const short8*)&Blds[(r0b)      * 128 + sb];
            short8 b1 = *(const short8*)&Blds[(r0b + 16) * 128 + sb];
            acc[0][0] = __builtin_amdgcn_mfma_f32_16x16x32_bf16(a0, b0, acc[0][0], 0, 0, 0);
            acc[0][1] = __builtin_amdgcn_mfma_f32_16x16x32_bf16(a0, b1, acc[0][1], 0, 0, 0);
            acc[1][0] = __builtin_amdgcn_mfma_f32_16x16x32_bf16(a1, b0, acc[1][0], 0, 0, 0);
            acc[1][1] = __builtin_amdgcn_mfma_f32_16x16x32_bf16(a1, b1, acc[1][1], 0, 0, 0);
        }
        __syncthreads();
    }

    const int rbase = (lane >> 4) * 4;
    const int cbase = lane & 15;
    #pragma unroll
    for (int i = 0; i < 2; i++) {
        #pragma unroll
        for (int j = 0; j < 2; j++) {
            const int gn = n0 + wc * 32 + j * 16 + cbase;
            #pragma unroll
            for (int q = 0; q < 4; q++) {
                const int gm = m0 + wr * 32 + i * 16 + rbase + q;
                part[(size_t)gm * NS + gn] = acc[i][j][q];
            }
        }
    }
}

// ---------------------------------------------------------------------------
// Epilogue: sum split-K partials; relu(main); for lam cols add
// softplus(b + lam_ment). Writes out[:, 2048:2560]. float4 over 2048x512.
// ---------------------------------------------------------------------------
__global__ __launch_bounds__(256) void epilogue(
    const float* __restrict__ mainpart, const float* __restrict__ lampart,
    const float* __restrict__ bvec, float* __restrict__ outp)
{
    const int idx = blockIdx.x * 256 + threadIdx.x;   // over 2048*128
    const int m = idx >> 7, n4 = idx & 127;
    const size_t mb = (size_t)m * 128 + n4;           // float4 units (NS=512)
    const size_t zs = (size_t)B_DIM * 128;
    float4 s = ((const float4*)mainpart)[mb];
    #pragma unroll
    for (int z = 1; z < 4; z++) {
        float4 t = ((const float4*)mainpart)[mb + z * zs];
        s.x += t.x; s.y += t.y; s.z += t.z; s.w += t.w;
    }
    s.x = fmaxf(s.x, 0.0f); s.y = fmaxf(s.y, 0.0f);
    s.z = fmaxf(s.z, 0.0f); s.w = fmaxf(s.w, 0.0f);
    if (n4 >= 64) {
        const int na = n4 - 64;                       // float4 idx in 256-col lam
        const size_t lb = (size_t)m * 64 + na;
        float4 l0 = ((const float4*)lampart)[lb];
        float4 l1 = ((const float4*)lampart)[lb + (size_t)B_DIM * 64];
        float4 bb = ((const float4*)bvec)[na];
        float x0 = bb.x + l0.x + l1.x, x1 = bb.y + l0.y + l1.y;
        float x2 = bb.z + l0.z + l1.z, x3 = bb.w + l0.w + l1.w;
        s.x += (x0 > 20.0f) ? x0 : log1pf(__expf(x0));
        s.y += (x1 > 20.0f) ? x1 : log1pf(__expf(x1));
        s.z += (x2 > 20.0f) ? x2 : log1pf(__expf(x2));
        s.w += (x3 > 20.0f) ? x3 : log1pf(__expf(x3));
    }
    ((float4*)(outp + (size_t)m * OUT_STRIDE + 2048))[n4] = s;
}

// ---------------------------------------------------------------------------
extern "C" void kernel_launch(void* const* d_in, const int* in_sizes, int n_in,
                              void* d_out, int out_size, void* d_ws, size_t ws_size,
                              hipStream_t stream)
{
    const float* M_minus = (const float*)d_in[0];
    const float* amask   = (const float*)d_in[1];
    const float* gate    = (const float*)d_in[2];
    const float* bmask   = (const float*)d_in[3];
    const float* isM     = (const float*)d_in[4];
    const float* isA     = (const float*)d_in[5];
    const float* GA      = (const float*)d_in[6];
    const float* GB      = (const float*)d_in[7];
    const float* bvec    = (const float*)d_in[8];
    const float* w       = (const float*)d_in[9];
    const int*   bidx    = (const int*)d_in[10];
    const int*   hidx    = (const int*)d_in[11];
    float* outp = (float*)d_out;

    char* ws = (char*)d_ws;
    unsigned short* g_bf   = (unsigned short*)(ws + 0);          // 16 MiB
    unsigned short* GAT    = (unsigned short*)(ws + (16u<<20));  // 2 MiB
    unsigned short* GBT    = (unsigned short*)(ws + (18u<<20));  // 2 MiB (contiguous after GAT)
    unsigned short* w_bf   = (unsigned short*)(ws + (20u<<20));  // 128 KiB
    unsigned short* mclip  = (unsigned short*)(ws + (21u<<20));  // 1 MiB
    float*          mainp  = (float*)(ws + (22u<<20));           // 4 x 4 MiB
    float*          lamp   = (float*)(ws + (38u<<20));           // 2 x 2 MiB

    prep_transpose<<<dim3(R_DIM / 32, 256 / 32, 2), dim3(256), 0, stream>>>(
        GA, GB, isM, isA, GAT, GBT);
    prep_cast_w<<<dim3((A_DIM * M_DIM) / 256), dim3(256), 0, stream>>>(w, w_bf);
    main_fused<<<dim3(B_DIM / NB), dim3(512), 0, stream>>>(
        M_minus, amask, gate, bmask, bidx, hidx, g_bf, mclip, outp);
    // lam_ment partials: Mclip @ w^T, K=256 split 2 -> 256 blocks (Kc=128)
    gemm_splitk<<<dim3(B_DIM / 64, A_DIM / 64, 2), dim3(256), 0, stream>>>(
        mclip, w_bf, lamp, M_DIM, A_DIM);
    // [S | lam_logic] partials: g @ [GAT|GBT]^T, K=4096 split 4 -> 1024 blocks
    gemm_splitk<<<dim3(B_DIM / 64, 512 / 64, 4), dim3(256), 0, stream>>>(
        g_bf, GAT, mainp, R_DIM, 512);
    epilogue<<<dim3((B_DIM * 128) / 256), dim3(256), 0, stream>>>(
        mainp, lamp, bvec, outp);
}

// Round 5
// 58.253 us; speedup vs baseline: 2.5772x; 1.0735x over previous
//
#include <hip/hip_runtime.h>

typedef __attribute__((ext_vector_type(8))) short short8;
typedef __attribute__((ext_vector_type(4))) float f32x4;

#define B_DIM 2048
#define P_DIM 2048
#define R_DIM 4096
#define H_DIM 6
#define M_DIM 256
#define A_DIM 256
#define OUT_STRIDE 2560   // P + M + A
#define NB 2              // batch rows per main_fused block
#define VSTRIDE 2064      // vrow row stride (sentinel at 2048; +16 bank offset)

static __device__ __forceinline__ unsigned short f2bf(float f) {
    unsigned u = __builtin_bit_cast(unsigned, f);
    u += 0x7fffu + ((u >> 16) & 1u);          // round-to-nearest-even
    return (unsigned short)(u >> 16);
}

// ---------------------------------------------------------------------------
// prep_all: one launch, block-range branching.
//   bid <  2048 : transpose+scale GA/GB -> GAT/GBT (bf16, N x K)
//   2048..2303  : cast w -> bf16
//   2304..2319  : pack rule metadata: 6x u16 idx (mask pre-applied ->
//                 sentinel 2048), u16 head (0xFFFF if >=256), u16 pad
// ---------------------------------------------------------------------------
__global__ __launch_bounds__(256) void prep_all(
    const float* __restrict__ GA, const float* __restrict__ GB,
    const float* __restrict__ isM, const float* __restrict__ isA,
    const float* __restrict__ w,
    const int* __restrict__ bidx, const float* __restrict__ bmask,
    const int* __restrict__ hidx,
    unsigned short* __restrict__ GAT, unsigned short* __restrict__ GBT,
    unsigned short* __restrict__ wb, uint4* __restrict__ meta)
{
    __shared__ float t[32][33];
    const int bid = blockIdx.x;
    if (bid < 2048) {
        const int which = bid >> 10;
        const int rem = bid & 1023;
        const float* src = which ? GB : GA;
        const float* scv = which ? isA : isM;
        unsigned short* dst = which ? GBT : GAT;
        const int r0 = (rem >> 3) * 32;   // K (=R) dim
        const int n0 = (rem & 7) * 32;    // N (=256) dim
        const int tx = threadIdx.x & 31, ty = threadIdx.x >> 5;
        #pragma unroll
        for (int q = 0; q < 4; q++) {
            int rr = ty + q * 8;
            t[rr][tx] = scv[r0 + rr] * src[(size_t)(r0 + rr) * 256 + n0 + tx];
        }
        __syncthreads();
        #pragma unroll
        for (int q = 0; q < 4; q++) {
            int nn = ty + q * 8;
            dst[(size_t)(n0 + nn) * R_DIM + r0 + tx] = f2bf(t[tx][nn]);
        }
    } else if (bid < 2304) {
        const int i = (bid - 2048) * 256 + threadIdx.x;   // 65536
        wb[i] = f2bf(w[i]);
    } else {
        const int r = (bid - 2304) * 256 + threadIdx.x;   // 4096
        const int* bi = bidx + r * H_DIM;
        const float* bm = bmask + r * H_DIM;
        unsigned s[H_DIM];
        #pragma unroll
        for (int h = 0; h < H_DIM; h++)
            s[h] = (bm[h] > 0.0f) ? (unsigned)bi[h] : 2048u;
        const int hh = hidx[r];
        unsigned sh = (hh < M_DIM) ? (unsigned)hh : 0xFFFFu;
        uint4 m;
        m.x = s[0] | (s[1] << 16);
        m.y = s[2] | (s[3] << 16);
        m.z = s[4] | (s[5] << 16);
        m.w = sh;
        meta[r] = m;
    }
}

// ---------------------------------------------------------------------------
// Main fused kernel: NB=2 rows/block, 512 threads, grid 1024, 32 waves/CU.
// Packed-meta single load per rule + explicit next-iteration prefetch.
// ---------------------------------------------------------------------------
__global__ __launch_bounds__(512, 8) void main_fused(
    const float* __restrict__ M_minus, const float* __restrict__ amask,
    const float* __restrict__ gate,    const uint4* __restrict__ meta,
    unsigned short* __restrict__ g_bf, unsigned short* __restrict__ mclip_bf,
    float* __restrict__ outp)
{
    __shared__ float vrow[NB][VSTRIDE];
    __shared__ float shead[NB][M_DIM];
    const int b0 = blockIdx.x * NB;
    const int tid = threadIdx.x;

    if (tid < M_DIM) {
        shead[0][tid] = 0.0f;
        shead[1][tid] = 0.0f;
    }
    if (tid < NB) vrow[tid][2048] = 1.0e4f;   // sentinel for masked bodies

    // phase 1: build NB val rows (one float4 per thread per row; 512 = P/4)
    #pragma unroll
    for (int r = 0; r < NB; r++) {
        const int c = tid;
        float4 v = ((const float4*)(amask + (size_t)(b0 + r) * P_DIM))[c];
        if (c < M_DIM / 4) {
            float4 m = ((const float4*)(M_minus + (size_t)(b0 + r) * M_DIM))[c];
            float mc0 = fminf(fmaxf(m.x, 0.0f), 1.0f);
            float mc1 = fminf(fmaxf(m.y, 0.0f), 1.0f);
            float mc2 = fminf(fmaxf(m.z, 0.0f), 1.0f);
            float mc3 = fminf(fmaxf(m.w, 0.0f), 1.0f);
            ushort4 mb; mb.x = f2bf(mc0); mb.y = f2bf(mc1); mb.z = f2bf(mc2); mb.w = f2bf(mc3);
            ((ushort4*)(mclip_bf + (size_t)(b0 + r) * M_DIM))[c] = mb;
            v.x = fmaxf(mc0, v.x); v.y = fmaxf(mc1, v.y);
            v.z = fmaxf(mc2, v.z); v.w = fmaxf(mc3, v.w);
        }
        ((float4*)vrow[r])[c] = v;
    }
    __syncthreads();

    // phase 2: rules, 8 iterations, software-pipelined (prefetch distance 1)
    const float* g0p = gate + (size_t)b0 * R_DIM;
    const float* g1p = gate + (size_t)(b0 + 1) * R_DIM;
    unsigned short* o0p = g_bf + (size_t)b0 * R_DIM;
    unsigned short* o1p = g_bf + (size_t)(b0 + 1) * R_DIM;

    uint4 mc = meta[tid];
    float ga = g0p[tid], gb = g1p[tid];
    #pragma unroll 2
    for (int it = 0; it < R_DIM / 512; it++) {
        const int rr = tid + it * 512;
        uint4 mn = mc; float gan = ga, gbn = gb;
        if (it < R_DIM / 512 - 1) {
            mn  = meta[rr + 512];
            gan = g0p[rr + 512];
            gbn = g1p[rr + 512];
        }
        const int i0 = mc.x & 0xFFFF, i1 = mc.x >> 16;
        const int i2 = mc.y & 0xFFFF, i3 = mc.y >> 16;
        const int i4 = mc.z & 0xFFFF, i5 = mc.z >> 16;
        const int hh = mc.w & 0xFFFF;
        // 12 independent gathers
        float x00 = vrow[0][i0], x01 = vrow[0][i1], x02 = vrow[0][i2];
        float x03 = vrow[0][i3], x04 = vrow[0][i4], x05 = vrow[0][i5];
        float x10 = vrow[1][i0], x11 = vrow[1][i1], x12 = vrow[1][i2];
        float x13 = vrow[1][i3], x14 = vrow[1][i4], x15 = vrow[1][i5];

        float vm0 = fminf(fminf(fminf(x00, x01), fminf(x02, x03)), fminf(x04, x05));
        float vm1 = fminf(fminf(fminf(x10, x11), fminf(x12, x13)), fminf(x14, x15));
        float s0 = __expf((vm0 - x00) * 10.0f) + __expf((vm0 - x01) * 10.0f)
                 + __expf((vm0 - x02) * 10.0f) + __expf((vm0 - x03) * 10.0f)
                 + __expf((vm0 - x04) * 10.0f) + __expf((vm0 - x05) * 10.0f);
        float s1 = __expf((vm1 - x10) * 10.0f) + __expf((vm1 - x11) * 10.0f)
                 + __expf((vm1 - x12) * 10.0f) + __expf((vm1 - x13) * 10.0f)
                 + __expf((vm1 - x14) * 10.0f) + __expf((vm1 - x15) * 10.0f);
        float gg0 = (vm0 - 0.1f * __logf(s0)) * ga;
        float gg1 = (vm1 - 0.1f * __logf(s1)) * gb;
        o0p[rr] = f2bf(gg0);
        o1p[rr] = f2bf(gg1);
        if (hh < M_DIM) {
            atomicAdd(&shead[0][hh], __expf(5.0f * gg0));   // BETA*g in [-0.9,5]
            atomicAdd(&shead[1][hh], __expf(5.0f * gg1));
        }
        mc = mn; ga = gan; gb = gbn;
    }
    __syncthreads();

    // phase 3: val_new columns of out
    #pragma unroll
    for (int r = 0; r < NB; r++) {
        const int c = tid;
        float4 v = ((const float4*)vrow[r])[c];
        if (c < M_DIM / 4) {
            int p = c * 4;
            float s0 = shead[r][p], s1 = shead[r][p+1], s2 = shead[r][p+2], s3 = shead[r][p+3];
            if (s0 > 0.0f) v.x = fmaxf(v.x, __logf(s0) * 0.2f);
            if (s1 > 0.0f) v.y = fmaxf(v.y, __logf(s1) * 0.2f);
            if (s2 > 0.0f) v.z = fmaxf(v.z, __logf(s2) * 0.2f);
            if (s3 > 0.0f) v.w = fmaxf(v.w, __logf(s3) * 0.2f);
        }
        ((float4*)(outp + (size_t)(b0 + r) * OUT_STRIDE))[c] = v;
    }
}

// ---------------------------------------------------------------------------
// global_load_lds 16B staging, XOR-swizzled source, linear LDS dest. BK=128.
// ---------------------------------------------------------------------------
__device__ __forceinline__ void stage16(unsigned short* lds,
                                        const unsigned short* gsrc,
                                        int K, int c)
{
    const int row = c >> 4, slot = c & 15;
    const int k8 = slot ^ (row & 15);      // logical 16B chunk at this slot
    __builtin_amdgcn_global_load_lds(
        (const __attribute__((address_space(1))) void*)(gsrc + (size_t)row * K + k8 * 8),
        (__attribute__((address_space(3))) void*)(lds + c * 8), 16, 0, 0);
}

// ---------------------------------------------------------------------------
// Main split-K GEMM: BM=128, BN=64, BK=128, 4 waves (wave tile 64x32).
// grid (M/128, N/64, z). part[z][m][n] f32.
// ---------------------------------------------------------------------------
__global__ __launch_bounds__(256) void gemm_main(
    const unsigned short* __restrict__ Ag,
    const unsigned short* __restrict__ Btg,
    float* __restrict__ part, int K, int NS)
{
    __shared__ __align__(16) unsigned short Alds[128 * 128];
    __shared__ __align__(16) unsigned short Blds[64 * 128];
    const int Kc = K / gridDim.z;
    const int k0 = blockIdx.z * Kc;
    part += (size_t)blockIdx.z * B_DIM * NS;
    const int m0 = blockIdx.x * 128, n0 = blockIdx.y * 64;
    const int tid = threadIdx.x;
    const int lane = tid & 63, wid = tid >> 6;
    const int wr = wid >> 1, wc = wid & 1;
    f32x4 acc[4][2] = {};

    for (int kt = 0; kt < Kc; kt += 128) {
        const unsigned short* Ab = Ag  + (size_t)m0 * K + k0 + kt;
        const unsigned short* Bb = Btg + (size_t)n0 * K + k0 + kt;
        #pragma unroll
        for (int q = 0; q < 8; q++) stage16(Alds, Ab, K, tid + q * 256);
        #pragma unroll
        for (int q = 0; q < 4; q++) stage16(Blds, Bb, K, tid + q * 256);
        __syncthreads();
        #pragma unroll
        for (int ks = 0; ks < 4; ks++) {
            const int k8 = ks * 4 + (lane >> 4);
            const int ra = wr * 64 + (lane & 15);
            const int rb = wc * 32 + (lane & 15);
            const int sa = (k8 ^ (ra & 15)) << 3;
            const int sb = (k8 ^ (rb & 15)) << 3;
            short8 a0 = *(const short8*)&Alds[(ra)      * 128 + sa];
            short8 a1 = *(const short8*)&Alds[(ra + 16) * 128 + sa];
            short8 a2 = *(const short8*)&Alds[(ra + 32) * 128 + sa];
            short8 a3 = *(const short8*)&Alds[(ra + 48) * 128 + sa];
            short8 b0 = *(const short8*)&Blds[(rb)      * 128 + sb];
            short8 b1 = *(const short8*)&Blds[(rb + 16) * 128 + sb];
            acc[0][0] = __builtin_amdgcn_mfma_f32_16x16x32_bf16(a0, b0, acc[0][0], 0, 0, 0);
            acc[0][1] = __builtin_amdgcn_mfma_f32_16x16x32_bf16(a0, b1, acc[0][1], 0, 0, 0);
            acc[1][0] = __builtin_amdgcn_mfma_f32_16x16x32_bf16(a1, b0, acc[1][0], 0, 0, 0);
            acc[1][1] = __builtin_amdgcn_mfma_f32_16x16x32_bf16(a1, b1, acc[1][1], 0, 0, 0);
            acc[2][0] = __builtin_amdgcn_mfma_f32_16x16x32_bf16(a2, b0, acc[2][0], 0, 0, 0);
            acc[2][1] = __builtin_amdgcn_mfma_f32_16x16x32_bf16(a2, b1, acc[2][1], 0, 0, 0);
            acc[3][0] = __builtin_amdgcn_mfma_f32_16x16x32_bf16(a3, b0, acc[3][0], 0, 0, 0);
            acc[3][1] = __builtin_amdgcn_mfma_f32_16x16x32_bf16(a3, b1, acc[3][1], 0, 0, 0);
        }
        __syncthreads();
    }

    const int rbase = (lane >> 4) * 4;
    const int cbase = lane & 15;
    #pragma unroll
    for (int i = 0; i < 4; i++) {
        #pragma unroll
        for (int j = 0; j < 2; j++) {
            const int gn = n0 + wc * 32 + j * 16 + cbase;
            #pragma unroll
            for (int q = 0; q < 4; q++) {
                const int gm = m0 + wr * 64 + i * 16 + rbase + q;
                part[(size_t)gm * NS + gn] = acc[i][j][q];
            }
        }
    }
}

// ---------------------------------------------------------------------------
// Small split-K GEMM (lam_ment): 64x64 tile, 4 waves, BK=128.
// ---------------------------------------------------------------------------
__global__ __launch_bounds__(256) void gemm_lam(
    const unsigned short* __restrict__ Ag,
    const unsigned short* __restrict__ Btg,
    float* __restrict__ part, int K, int NS)
{
    __shared__ __align__(16) unsigned short Alds[64 * 128];
    __shared__ __align__(16) unsigned short Blds[64 * 128];
    const int Kc = K / gridDim.z;
    const int k0 = blockIdx.z * Kc;
    part += (size_t)blockIdx.z * B_DIM * NS;
    const int m0 = blockIdx.x * 64, n0 = blockIdx.y * 64;
    const int tid = threadIdx.x;
    const int lane = tid & 63, wid = tid >> 6;
    const int wr = wid >> 1, wc = wid & 1;
    f32x4 acc[2][2] = {};

    for (int kt = 0; kt < Kc; kt += 128) {
        const unsigned short* Ab = Ag  + (size_t)m0 * K + k0 + kt;
        const unsigned short* Bb = Btg + (size_t)n0 * K + k0 + kt;
        #pragma unroll
        for (int q = 0; q < 4; q++) {
            stage16(Alds, Ab, K, tid + q * 256);
            stage16(Blds, Bb, K, tid + q * 256);
        }
        __syncthreads();
        #pragma unroll
        for (int ks = 0; ks < 4; ks++) {
            const int k8 = ks * 4 + (lane >> 4);
            const int r0a = wr * 32 + (lane & 15);
            const int r0b = wc * 32 + (lane & 15);
            const int sa = (k8 ^ (r0a & 15)) << 3;
            const int sb = (k8 ^ (r0b & 15)) << 3;
            short8 a0 = *(const short8*)&Alds[(r0a)      * 128 + sa];
            short8 a1 = *(const short8*)&Alds[(r0a + 16) * 128 + sa];
            short8 b0 = *(const short8*)&Blds[(r0b)      * 128 + sb];
            short8 b1 = *(const short8*)&Blds[(r0b + 16) * 128 + sb];
            acc[0][0] = __builtin_amdgcn_mfma_f32_16x16x32_bf16(a0, b0, acc[0][0], 0, 0, 0);
            acc[0][1] = __builtin_amdgcn_mfma_f32_16x16x32_bf16(a0, b1, acc[0][1], 0, 0, 0);
            acc[1][0] = __builtin_amdgcn_mfma_f32_16x16x32_bf16(a1, b0, acc[1][0], 0, 0, 0);
            acc[1][1] = __builtin_amdgcn_mfma_f32_16x16x32_bf16(a1, b1, acc[1][1], 0, 0, 0);
        }
        __syncthreads();
    }

    const int rbase = (lane >> 4) * 4;
    const int cbase = lane & 15;
    #pragma unroll
    for (int i = 0; i < 2; i++) {
        #pragma unroll
        for (int j = 0; j < 2; j++) {
            const int gn = n0 + wc * 32 + j * 16 + cbase;
            #pragma unroll
            for (int q = 0; q < 4; q++) {
                const int gm = m0 + wr * 32 + i * 16 + rbase + q;
                part[(size_t)gm * NS + gn] = acc[i][j][q];
            }
        }
    }
}

// ---------------------------------------------------------------------------
// Epilogue: sum split-K partials; relu(main); lam cols += softplus(b+lam_ment)
// ---------------------------------------------------------------------------
__global__ __launch_bounds__(256) void epilogue(
    const float* __restrict__ mainpart, const float* __restrict__ lampart,
    const float* __restrict__ bvec, float* __restrict__ outp)
{
    const int idx = blockIdx.x * 256 + threadIdx.x;   // over 2048*128
    const int m = idx >> 7, n4 = idx & 127;
    const size_t mb = (size_t)m * 128 + n4;           // float4 units (NS=512)
    const size_t zs = (size_t)B_DIM * 128;
    float4 s = ((const float4*)mainpart)[mb];
    #pragma unroll
    for (int z = 1; z < 4; z++) {
        float4 t = ((const float4*)mainpart)[mb + z * zs];
        s.x += t.x; s.y += t.y; s.z += t.z; s.w += t.w;
    }
    s.x = fmaxf(s.x, 0.0f); s.y = fmaxf(s.y, 0.0f);
    s.z = fmaxf(s.z, 0.0f); s.w = fmaxf(s.w, 0.0f);
    if (n4 >= 64) {
        const int na = n4 - 64;                       // float4 idx in 256-col lam
        const size_t lb = (size_t)m * 64 + na;
        float4 l0 = ((const float4*)lampart)[lb];
        float4 l1 = ((const float4*)lampart)[lb + (size_t)B_DIM * 64];
        float4 bb = ((const float4*)bvec)[na];
        float x0 = bb.x + l0.x + l1.x, x1 = bb.y + l0.y + l1.y;
        float x2 = bb.z + l0.z + l1.z, x3 = bb.w + l0.w + l1.w;
        s.x += (x0 > 20.0f) ? x0 : log1pf(__expf(x0));
        s.y += (x1 > 20.0f) ? x1 : log1pf(__expf(x1));
        s.z += (x2 > 20.0f) ? x2 : log1pf(__expf(x2));
        s.w += (x3 > 20.0f) ? x3 : log1pf(__expf(x3));
    }
    ((float4*)(outp + (size_t)m * OUT_STRIDE + 2048))[n4] = s;
}

// ---------------------------------------------------------------------------
extern "C" void kernel_launch(void* const* d_in, const int* in_sizes, int n_in,
                              void* d_out, int out_size, void* d_ws, size_t ws_size,
                              hipStream_t stream)
{
    const float* M_minus = (const float*)d_in[0];
    const float* amask   = (const float*)d_in[1];
    const float* gate    = (const float*)d_in[2];
    const float* bmask   = (const float*)d_in[3];
    const float* isM     = (const float*)d_in[4];
    const float* isA     = (const float*)d_in[5];
    const float* GA      = (const float*)d_in[6];
    const float* GB      = (const float*)d_in[7];
    const float* bvec    = (const float*)d_in[8];
    const float* w       = (const float*)d_in[9];
    const int*   bidx    = (const int*)d_in[10];
    const int*   hidx    = (const int*)d_in[11];
    float* outp = (float*)d_out;

    char* ws = (char*)d_ws;
    unsigned short* g_bf   = (unsigned short*)(ws + 0);          // 16 MiB
    unsigned short* GAT    = (unsigned short*)(ws + (16u<<20));  // 2 MiB
    unsigned short* GBT    = (unsigned short*)(ws + (18u<<20));  // 2 MiB (contiguous after GAT)
    unsigned short* w_bf   = (unsigned short*)(ws + (20u<<20));  // 128 KiB
    uint4*          meta   = (uint4*)(ws + (20u<<20) + (256u<<10)); // 64 KiB
    unsigned short* mclip  = (unsigned short*)(ws + (21u<<20));  // 1 MiB
    float*          mainp  = (float*)(ws + (22u<<20));           // 4 x 4 MiB
    float*          lamp   = (float*)(ws + (38u<<20));           // 2 x 2 MiB

    prep_all<<<dim3(2320), dim3(256), 0, stream>>>(
        GA, GB, isM, isA, w, bidx, bmask, hidx, GAT, GBT, w_bf, meta);
    main_fused<<<dim3(B_DIM / NB), dim3(512), 0, stream>>>(
        M_minus, amask, gate, meta, g_bf, mclip, outp);
    // lam_ment partials: Mclip @ w^T, K=256 split 2 (Kc=128)
    gemm_lam<<<dim3(B_DIM / 64, A_DIM / 64, 2), dim3(256), 0, stream>>>(
        mclip, w_bf, lamp, M_DIM, A_DIM);
    // [S | lam_logic] partials: g @ [GAT|GBT]^T, K=4096 split 4 -> 512 blocks
    gemm_main<<<dim3(B_DIM / 128, 512 / 64, 4), dim3(256), 0, stream>>>(
        g_bf, GAT, mainp, R_DIM, 512);
    epilogue<<<dim3((B_DIM * 128) / 256), dim3(256), 0, stream>>>(
        mainp, lamp, bvec, outp);
}